// Round 2
// baseline (735.179 us; speedup 1.0000x reference)
//
#include <hip/hip_runtime.h>
#include <math.h>

#define NROWS (64 * 4096)        // 262144 rows
#define D     64
#define K     1024
#define CHUNK 128                // codes staged in LDS per iteration (32 KB)
#define NELEM ((size_t)NROWS * (size_t)D)   // 16777216

// ws layout (bytes):
// [0,     4096)  float norms[1024]
// [4096,  8192)  uint  counts[1024]        (zeroed each call)
// [8192, 12288)  float block_loss[1024]    (every block writes -> no zeroing needed)

#define DOT4(acc, a, e) \
  acc = fmaf((a).x, (e).x, fmaf((a).y, (e).y, fmaf((a).z, (e).z, fmaf((a).w, (e).w, (acc)))))

#define SQD4(acc, a, e) { \
  float _dx = (e).x - (a).x, _dy = (e).y - (a).y, _dz = (e).z - (a).z, _dw = (e).w - (a).w; \
  acc = fmaf(_dx, _dx, fmaf(_dy, _dy, fmaf(_dz, _dz, fmaf(_dw, _dw, (acc))))); }

__global__ __launch_bounds__(256) void vq_norms(const float* __restrict__ cb,
                                                float* __restrict__ norms) {
  int k = blockIdx.x * blockDim.x + threadIdx.x;
  if (k >= K) return;
  const float4* e4 = (const float4*)(cb + (k << 6));
  float a0 = 0.f, a1 = 0.f, a2 = 0.f, a3 = 0.f;
#pragma unroll
  for (int j = 0; j < 16; j += 4) {
    float4 e;
    e = e4[j + 0]; DOT4(a0, e, e);
    e = e4[j + 1]; DOT4(a1, e, e);
    e = e4[j + 2]; DOT4(a2, e, e);
    e = e4[j + 3]; DOT4(a3, e, e);
  }
  norms[k] = (a0 + a1) + (a2 + a3);
}

__global__ __launch_bounds__(256, 4) void vq_main(const float* __restrict__ z,
                                                  const float* __restrict__ cb,
                                                  const float* __restrict__ norms,
                                                  float* __restrict__ zq,
                                                  unsigned int* __restrict__ counts,
                                                  float* __restrict__ block_loss) {
  __shared__ float scb[CHUNK * D];     // 32 KB codebook chunk
  __shared__ float snorm[CHUNK];       // 512 B
  __shared__ float red[256];

  const int tid = threadIdx.x;
  const int row = blockIdx.x * 256 + tid;

  // z row into registers (64 VGPRs; launch_bounds(256,4) gives 128-VGPR budget)
  const float4* zr4 = (const float4*)(z + (size_t)row * D);
  float4 zr[16];
#pragma unroll
  for (int j = 0; j < 16; ++j) zr[j] = zr4[j];

  // argmin over k of  m_k = ||e_k||^2 - 2 z.e_k   (||z||^2 is row-constant)
  float best = 3.4e38f;
  int   bidx = 0;

  for (int c0 = 0; c0 < K; c0 += CHUNK) {
    __syncthreads();   // protect LDS reads of previous chunk
    // cooperative load: CHUNK*D floats = 8192 floats = 2048 float4; 8 float4/thread
    {
      const float4* src = (const float4*)(cb + (size_t)c0 * D);
      float4* dst = (float4*)scb;
#pragma unroll
      for (int j = 0; j < 8; ++j) dst[tid + 256 * j] = src[tid + 256 * j];
      if (tid < CHUNK) snorm[tid] = norms[c0 + tid];
    }
    __syncthreads();

    for (int kk = 0; kk < CHUNK; kk += 2) {
      const float4* e0 = (const float4*)(scb + (kk << 6));
      const float4* e1 = e0 + 16;
      float a0 = 0.f, a1 = 0.f, a2 = 0.f, a3 = 0.f;
      float b0 = 0.f, b1 = 0.f, b2 = 0.f, b3 = 0.f;
#pragma unroll
      for (int j = 0; j < 16; j += 4) {
        float4 t;
        t = e0[j + 0]; DOT4(a0, zr[j + 0], t);
        t = e1[j + 0]; DOT4(b0, zr[j + 0], t);
        t = e0[j + 1]; DOT4(a1, zr[j + 1], t);
        t = e1[j + 1]; DOT4(b1, zr[j + 1], t);
        t = e0[j + 2]; DOT4(a2, zr[j + 2], t);
        t = e1[j + 2]; DOT4(b2, zr[j + 2], t);
        t = e0[j + 3]; DOT4(a3, zr[j + 3], t);
        t = e1[j + 3]; DOT4(b3, zr[j + 3], t);
      }
      float d0 = (a0 + a1) + (a2 + a3);
      float d1 = (b0 + b1) + (b2 + b3);
      float m0 = fmaf(-2.f, d0, snorm[kk]);
      float m1 = fmaf(-2.f, d1, snorm[kk + 1]);
      if (m0 < best) { best = m0; bidx = c0 + kk; }      // strict < == np.argmin first-index
      if (m1 < best) { best = m1; bidx = c0 + kk + 1; }
    }
  }

  // epilogue: gather winning code, write z_q, exact row loss
  const float4* eb4 = (const float4*)(cb + ((size_t)bidx << 6));
  float4* o4 = (float4*)(zq + (size_t)row * D);
  float l0 = 0.f, l1 = 0.f, l2 = 0.f, l3 = 0.f;
#pragma unroll
  for (int j = 0; j < 16; j += 4) {
    float4 e;
    e = eb4[j + 0]; o4[j + 0] = e; SQD4(l0, zr[j + 0], e);
    e = eb4[j + 1]; o4[j + 1] = e; SQD4(l1, zr[j + 1], e);
    e = eb4[j + 2]; o4[j + 2] = e; SQD4(l2, zr[j + 2], e);
    e = eb4[j + 3]; o4[j + 3] = e; SQD4(l3, zr[j + 3], e);
  }
  float row_loss = (l0 + l1) + (l2 + l3);

  atomicAdd(&counts[bidx], 1u);   // integer atomics: deterministic

  // deterministic block reduction of row_loss
  red[tid] = row_loss;
  __syncthreads();
#pragma unroll
  for (int s = 128; s > 0; s >>= 1) {
    if (tid < s) red[tid] += red[tid + s];
    __syncthreads();
  }
  if (tid == 0) block_loss[blockIdx.x] = red[0];
}

__global__ __launch_bounds__(1024) void vq_finalize(const unsigned int* __restrict__ counts,
                                                    const float* __restrict__ block_loss,
                                                    float* __restrict__ out) {
  __shared__ float sh[1024];
  __shared__ float sl[1024];
  const int t = threadIdx.x;
  float c = (float)counts[t];
  float p = c * (1.0f / (float)NROWS);
  sh[t] = p * logf(p + 1e-10f);
  sl[t] = block_loss[t];
  __syncthreads();
#pragma unroll
  for (int s = 512; s > 0; s >>= 1) {
    if (t < s) { sh[t] += sh[t + s]; sl[t] += sl[t + s]; }
    __syncthreads();
  }
  if (t == 0) {
    out[NELEM]     = 1.25f * sl[0] / (float)NELEM;  // q_loss + 0.25*e_loss, both == mean sq diff
    out[NELEM + 1] = expf(-sh[0]);                  // perplexity
  }
}

extern "C" void kernel_launch(void* const* d_in, const int* in_sizes, int n_in,
                              void* d_out, int out_size, void* d_ws, size_t ws_size,
                              hipStream_t stream) {
  const float* z  = (const float*)d_in[0];   // [262144, 64]
  const float* cb = (const float*)d_in[1];   // [1024, 64]
  float* out = (float*)d_out;                // [16777216 z_q | loss | perplexity]

  float*        norms      = (float*)d_ws;
  unsigned int* counts     = (unsigned int*)((char*)d_ws + 4096);
  float*        block_loss = (float*)((char*)d_ws + 8192);

  hipMemsetAsync((char*)d_ws + 4096, 0, 4096, stream);   // zero counts
  vq_norms<<<dim3(4), dim3(256), 0, stream>>>(cb, norms);
  vq_main<<<dim3(NROWS / 256), dim3(256), 0, stream>>>(z, cb, norms, out, counts, block_loss);
  vq_finalize<<<dim3(1), dim3(1024), 0, stream>>>(counts, block_loss, out);
}

// Round 3
// 199.610 us; speedup vs baseline: 3.6831x; 3.6831x over previous
//
#include <hip/hip_runtime.h>
#include <math.h>

#define NROWS   (64 * 4096)                 // 262144 rows
#define D       64
#define K       1024
#define NELEM   ((size_t)NROWS * (size_t)D) // 16777216

// ---- MFMA-path geometry ----
#define CHUNK_CODES 128
#define ROWB        144                       // padded code row bytes (72 bf16)
#define CBH_BYTES   (CHUNK_CODES * ROWB)      // 18432
#define REC_BYTES   (CBH_BYTES * 2 + 512)     // hi + lo + 128 norms = 37376
#define NCHUNK      (K / CHUNK_CODES)         // 8
#define WS_CHUNK_OFF 16384
#define WS_MAIN_NEED (WS_CHUNK_OFF + NCHUNK * REC_BYTES)   // 315392
#define BLK_ROWS    128                       // rows per block (4 waves x 32)
#define NBLOCKS     (NROWS / BLK_ROWS)        // 2048

#define GAP_THRESH 8.0e-3f                    // 2*EPS, EPS=4e-3 (bound ~8e-4, 10x margin)

typedef float  f32x4  __attribute__((ext_vector_type(4)));
typedef short  s16x8  __attribute__((ext_vector_type(8)));

// ws layout (main path, bytes):
// [0,4096)        uint counts[1024]   (zeroed per call)
// [4096,12288)    float block_loss[2048]
// [16384, +8*37376) chunk records: per chunk {cbh 128x144B | cbl 128x144B | norms 128xf32}
// fallback path:  [12288,16384) float norms[1024]

static __device__ inline unsigned bf16_rne(unsigned u) {
  return (u + 0x7FFFu + ((u >> 16) & 1u)) >> 16;
}

// ---------------- prep: split codebook into bf16 hi/lo chunk records -------------
__global__ __launch_bounds__(256) void vq_prep(const float* __restrict__ cb,
                                               char* __restrict__ ws) {
  int k = blockIdx.x * 256 + threadIdx.x;
  if (k >= K) return;
  int chunk = k >> 7, cc = k & 127;
  char* rec = ws + WS_CHUNK_OFF + chunk * REC_BYTES;
  unsigned short* hrow = (unsigned short*)(rec + cc * ROWB);
  unsigned short* lrow = (unsigned short*)(rec + CBH_BYTES + cc * ROWB);
  const float* src = cb + (k << 6);
  float nrm = 0.f;
  for (int j = 0; j < 64; j += 2) {
    float x0 = src[j], x1 = src[j + 1];
    nrm = fmaf(x0, x0, fmaf(x1, x1, nrm));
    unsigned h0 = bf16_rne(__float_as_uint(x0));
    unsigned h1 = bf16_rne(__float_as_uint(x1));
    float hf0 = __uint_as_float(h0 << 16), hf1 = __uint_as_float(h1 << 16);
    unsigned l0 = bf16_rne(__float_as_uint(x0 - hf0));
    unsigned l1 = bf16_rne(__float_as_uint(x1 - hf1));
    *(unsigned*)(hrow + j) = h0 | (h1 << 16);
    *(unsigned*)(lrow + j) = l0 | (l1 << 16);
  }
  *(float*)(rec + 2 * CBH_BYTES + cc * 4) = nrm;
}

// ---------------- main MFMA kernel -------------
__global__ __launch_bounds__(256, 4) void vq_mfma(const float* __restrict__ z,
                                                  const float* __restrict__ cb,
                                                  const char* __restrict__ ws,
                                                  float* __restrict__ zq,
                                                  unsigned int* __restrict__ counts,
                                                  float* __restrict__ block_loss) {
  __shared__ __align__(16) char sblob[REC_BYTES];
  __shared__ int   sk[BLK_ROWS];
  __shared__ float red[256];

  const int t    = threadIdx.x;
  const int w    = t >> 6;          // wave 0..3
  const int lane = t & 63;
  const int g    = lane >> 4;       // k-group 0..3
  const int ln16 = lane & 15;

  // ---- load z rows (2 row-tiles x 16 rows) and split to bf16 hi/lo frags ----
  // B-frag: lane holds z[row = base + rt*16 + ln16][k = ks*32 + g*8 + j], j=0..7
  const int rowbase = blockIdx.x * BLK_ROWS + w * 32;
  s16x8 zh[2][2], zl[2][2];
#pragma unroll
  for (int rt = 0; rt < 2; ++rt) {
    int row = rowbase + rt * 16 + ln16;
    const float4* zr = (const float4*)(z + row * 64);
#pragma unroll
    for (int ks = 0; ks < 2; ++ks) {
      float4 a = zr[ks * 8 + g * 2];
      float4 b = zr[ks * 8 + g * 2 + 1];
      float xs[8] = {a.x, a.y, a.z, a.w, b.x, b.y, b.z, b.w};
      s16x8 hh, ll;
#pragma unroll
      for (int j = 0; j < 8; ++j) {
        unsigned hb = bf16_rne(__float_as_uint(xs[j]));
        float hf = __uint_as_float(hb << 16);
        unsigned lb = bf16_rne(__float_as_uint(xs[j] - hf));
        hh[j] = (short)hb; ll[j] = (short)lb;
      }
      zh[rt][ks] = hh; zl[rt][ks] = ll;
    }
  }

  // per-row-tile min tracking (codes this lane sees: k ≡ g*4..g*4+3 mod 16)
  float m1v0 = 3.4e38f, m2v0 = 3.4e38f, m3v0 = 3.4e38f;
  float m1v1 = 3.4e38f, m2v1 = 3.4e38f, m3v1 = 3.4e38f;
  int   m1i0 = 0, m2i0 = 0, m1i1 = 0, m2i1 = 0;

  const int aoff = ln16 * ROWB + g * 16;   // A-frag byte offset within code rows

  for (int c = 0; c < NCHUNK; ++c) {
    __syncthreads();
    {
      const float4* src = (const float4*)(ws + WS_CHUNK_OFF + c * REC_BYTES);
      float4* dst = (float4*)sblob;
#pragma unroll
      for (int i = 0; i < 10; ++i) {
        int idx = t + 256 * i;
        if (idx < REC_BYTES / 16) dst[idx] = src[idx];
      }
    }
    __syncthreads();

#pragma unroll
    for (int tl = 0; tl < CHUNK_CODES / 16; ++tl) {
      const char* ab = sblob + tl * 16 * ROWB + aoff;
      s16x8 eh0 = *(const s16x8*)(ab);
      s16x8 eh1 = *(const s16x8*)(ab + 64);
      s16x8 el0 = *(const s16x8*)(ab + CBH_BYTES);
      s16x8 el1 = *(const s16x8*)(ab + CBH_BYTES + 64);
      f32x4 nrm = *(const f32x4*)(sblob + 2 * CBH_BYTES + tl * 64 + g * 16);

      f32x4 acc0 = {0.f, 0.f, 0.f, 0.f}, acc1 = {0.f, 0.f, 0.f, 0.f};
      acc0 = __builtin_amdgcn_mfma_f32_16x16x32_bf16(eh0, zh[0][0], acc0, 0, 0, 0);
      acc1 = __builtin_amdgcn_mfma_f32_16x16x32_bf16(eh0, zh[1][0], acc1, 0, 0, 0);
      acc0 = __builtin_amdgcn_mfma_f32_16x16x32_bf16(eh1, zh[0][1], acc0, 0, 0, 0);
      acc1 = __builtin_amdgcn_mfma_f32_16x16x32_bf16(eh1, zh[1][1], acc1, 0, 0, 0);
      acc0 = __builtin_amdgcn_mfma_f32_16x16x32_bf16(el0, zh[0][0], acc0, 0, 0, 0);
      acc1 = __builtin_amdgcn_mfma_f32_16x16x32_bf16(el0, zh[1][0], acc1, 0, 0, 0);
      acc0 = __builtin_amdgcn_mfma_f32_16x16x32_bf16(el1, zh[0][1], acc0, 0, 0, 0);
      acc1 = __builtin_amdgcn_mfma_f32_16x16x32_bf16(el1, zh[1][1], acc1, 0, 0, 0);
      acc0 = __builtin_amdgcn_mfma_f32_16x16x32_bf16(eh0, zl[0][0], acc0, 0, 0, 0);
      acc1 = __builtin_amdgcn_mfma_f32_16x16x32_bf16(eh0, zl[1][0], acc1, 0, 0, 0);
      acc0 = __builtin_amdgcn_mfma_f32_16x16x32_bf16(eh1, zl[0][1], acc0, 0, 0, 0);
      acc1 = __builtin_amdgcn_mfma_f32_16x16x32_bf16(eh1, zl[1][1], acc1, 0, 0, 0);

      const int kbase = c * CHUNK_CODES + tl * 16 + g * 4;
#define UPD(RT, R) {                                                        \
        float m = fmaf(-2.f, acc##RT[R], nrm[R]);                           \
        int   kk = kbase + R;                                               \
        bool lt1 = m < m1v##RT;                                             \
        bool lt2 = m < m2v##RT;                                             \
        float o1v = m1v##RT; int o1i = m1i##RT; float o2v = m2v##RT;        \
        m3v##RT = fminf(m3v##RT, fmaxf(o2v, m));                            \
        m2v##RT = lt1 ? o1v : (lt2 ? m : o2v);                              \
        m2i##RT = lt1 ? o1i : (lt2 ? kk : m2i##RT);                         \
        m1v##RT = lt1 ? m : o1v;                                            \
        m1i##RT = lt1 ? kk : o1i;                                           \
      }
      UPD(0, 0) UPD(0, 1) UPD(0, 2) UPD(0, 3)
      UPD(1, 0) UPD(1, 1) UPD(1, 2) UPD(1, 3)
#undef UPD
    }
  }

  // ---- per-row finish: cross-lane merge, decide, rescore ----
  const float4* cb4 = (const float4*)cb;
  const float4* z4g = (const float4*)z;
#pragma unroll
  for (int rt = 0; rt < 2; ++rt) {
    float m1 = rt ? m1v1 : m1v0;  int i1 = rt ? m1i1 : m1i0;
    float m2 = rt ? m2v1 : m2v0;  int i2 = rt ? m2i1 : m2i0;
    float m3 = rt ? m3v1 : m3v0;
#pragma unroll
    for (int dx = 16; dx <= 32; dx <<= 1) {
      float o1 = __shfl_xor(m1, dx); int oi1 = __shfl_xor(i1, dx);
      float o2 = __shfl_xor(m2, dx); int oi2 = __shfl_xor(i2, dx);
      float o3 = __shfl_xor(m3, dx);
      float nm3 = fminf(fminf(m3, o3), fminf(fmaxf(m2, o1), fmaxf(o2, m1)));
      bool take1 = (o1 < m1) || (o1 == m1 && oi1 < i1);
      float hi1v = take1 ? m1 : o1; int hi1i = take1 ? i1 : oi1;
      float nm1  = take1 ? o1 : m1; int ni1  = take1 ? oi1 : i1;
      bool h2 = (m2 < o2) || (m2 == o2 && i2 < oi2);
      float c2v = h2 ? m2 : o2; int c2i = h2 ? i2 : oi2;
      bool hb2 = (hi1v < c2v) || (hi1v == c2v && hi1i < c2i);
      float nm2 = hb2 ? hi1v : c2v; int ni2 = hb2 ? hi1i : c2i;
      m1 = nm1; i1 = ni1; m2 = nm2; i2 = ni2; m3 = nm3;
    }
    // all lanes hold identical merged results now
    bool needFull = (m3 - m1) < GAP_THRESH;
    bool needPair = !needFull && ((m2 - m1) < GAP_THRESH);
    int  kstar = i1;

    if (g == 0) {
      int row = rowbase + rt * 16 + ln16;   // global row
      if (needPair) {
        float d1 = 0.f, d2 = 0.f;
        const float4* zr = z4g + row * 16;
        const float4* c1 = cb4 + i1 * 16;
        const float4* c2 = cb4 + i2 * 16;
#pragma unroll
        for (int j = 0; j < 16; ++j) {
          float4 zv = zr[j], a = c1[j], b = c2[j];
          float e;
          e = zv.x - a.x; d1 = fmaf(e, e, d1);
          e = zv.y - a.y; d1 = fmaf(e, e, d1);
          e = zv.z - a.z; d1 = fmaf(e, e, d1);
          e = zv.w - a.w; d1 = fmaf(e, e, d1);
          e = zv.x - b.x; d2 = fmaf(e, e, d2);
          e = zv.y - b.y; d2 = fmaf(e, e, d2);
          e = zv.z - b.z; d2 = fmaf(e, e, d2);
          e = zv.w - b.w; d2 = fmaf(e, e, d2);
        }
        if (d2 < d1 || (d2 == d1 && i2 < i1)) kstar = i2;
      }
      if (!needFull) {
        int lrow = w * 32 + rt * 16 + ln16;
        sk[lrow] = kstar;
        atomicAdd(&counts[kstar], 1u);
      }
    }

    // wave-cooperative full rescan for flagged rows
    unsigned long long fullmask = __ballot(needFull && g == 0);
    while (fullmask) {
      int src = __ffsll(fullmask) - 1;
      fullmask &= fullmask - 1;
      int lrow = w * 32 + rt * 16 + src;
      int row  = blockIdx.x * BLK_ROWS + lrow;
      const float4* zr = z4g + row * 16;
      float bv = 3.4e38f; int bi = 0;
      for (int c16 = 0; c16 < 16; ++c16) {
        int code = c16 * 64 + lane;
        const float4* cr = cb4 + code * 16;
        float d = 0.f;
#pragma unroll
        for (int j = 0; j < 16; ++j) {
          float4 zv = zr[j], cv = cr[j];
          float e;
          e = zv.x - cv.x; d = fmaf(e, e, d);
          e = zv.y - cv.y; d = fmaf(e, e, d);
          e = zv.z - cv.z; d = fmaf(e, e, d);
          e = zv.w - cv.w; d = fmaf(e, e, d);
        }
        if (d < bv) { bv = d; bi = code; }
      }
#pragma unroll
      for (int dx = 1; dx < 64; dx <<= 1) {
        float ov = __shfl_xor(bv, dx); int oi = __shfl_xor(bi, dx);
        if (ov < bv || (ov == bv && oi < bi)) { bv = ov; bi = oi; }
      }
      if (lane == 0) { sk[lrow] = bi; atomicAdd(&counts[bi], 1u); }
    }
  }

  __syncthreads();

  // ---- cooperative z_q write + exact loss ----
  float lpart = 0.f;
  const int base4 = blockIdx.x * (BLK_ROWS * 16);
  float4* out4 = (float4*)zq;
#pragma unroll
  for (int i = 0; i < 8; ++i) {
    int idx = t + 256 * i;            // [0, 2048)
    int row = idx >> 4, c4 = idx & 15;
    int kk = sk[row];
    float4 cv = cb4[kk * 16 + c4];
    float4 zv = z4g[base4 + idx];
    float e;
    e = zv.x - cv.x; lpart = fmaf(e, e, lpart);
    e = zv.y - cv.y; lpart = fmaf(e, e, lpart);
    e = zv.z - cv.z; lpart = fmaf(e, e, lpart);
    e = zv.w - cv.w; lpart = fmaf(e, e, lpart);
    out4[base4 + idx] = cv;
  }
  red[t] = lpart;
  __syncthreads();
#pragma unroll
  for (int s = 128; s > 0; s >>= 1) {
    if (t < s) red[t] += red[t + s];
    __syncthreads();
  }
  if (t == 0) block_loss[blockIdx.x] = red[0];
}

// ---------------- finalize -------------
__global__ __launch_bounds__(1024) void vq_finalize(const unsigned int* __restrict__ counts,
                                                    const float* __restrict__ block_loss,
                                                    float* __restrict__ out, int nb) {
  __shared__ float sh[1024];
  __shared__ float sl[1024];
  const int t = threadIdx.x;
  float c = (float)counts[t];
  float p = c * (1.0f / (float)NROWS);
  sh[t] = p * logf(p + 1e-10f);
  float bl = (t < nb) ? block_loss[t] : 0.f;
  if (t + 1024 < nb) bl += block_loss[t + 1024];
  sl[t] = bl;
  __syncthreads();
#pragma unroll
  for (int s = 512; s > 0; s >>= 1) {
    if (t < s) { sh[t] += sh[t + s]; sl[t] += sl[t + s]; }
    __syncthreads();
  }
  if (t == 0) {
    out[NELEM]     = 1.25f * sl[0] / (float)NELEM;
    out[NELEM + 1] = expf(-sh[0]);
  }
}

// ---------------- fallback (small ws): R1 fp32 kernel -------------
#define DOT4(acc, a, e) \
  acc = fmaf((a).x, (e).x, fmaf((a).y, (e).y, fmaf((a).z, (e).z, fmaf((a).w, (e).w, (acc)))))
#define SQD4(acc, a, e) { \
  float _dx = (e).x - (a).x, _dy = (e).y - (a).y, _dz = (e).z - (a).z, _dw = (e).w - (a).w; \
  acc = fmaf(_dx, _dx, fmaf(_dy, _dy, fmaf(_dz, _dz, fmaf(_dw, _dw, (acc))))); }

__global__ __launch_bounds__(256) void vq_norms_fb(const float* __restrict__ cb,
                                                   float* __restrict__ norms) {
  int k = blockIdx.x * blockDim.x + threadIdx.x;
  if (k >= K) return;
  const float4* e4 = (const float4*)(cb + (k << 6));
  float a0 = 0.f, a1 = 0.f, a2 = 0.f, a3 = 0.f;
#pragma unroll
  for (int j = 0; j < 16; j += 4) {
    float4 e;
    e = e4[j + 0]; DOT4(a0, e, e);
    e = e4[j + 1]; DOT4(a1, e, e);
    e = e4[j + 2]; DOT4(a2, e, e);
    e = e4[j + 3]; DOT4(a3, e, e);
  }
  norms[k] = (a0 + a1) + (a2 + a3);
}

__global__ __launch_bounds__(256) void vq_main_fb(const float* __restrict__ z,
                                                  const float* __restrict__ cb,
                                                  const float* __restrict__ norms,
                                                  float* __restrict__ zq,
                                                  unsigned int* __restrict__ counts,
                                                  float* __restrict__ block_loss) {
  const int tid = threadIdx.x;
  const int row = blockIdx.x * 256 + tid;
  const float4* zr4 = (const float4*)(z + (size_t)row * D);
  float4 zr[16];
#pragma unroll
  for (int j = 0; j < 16; ++j) zr[j] = zr4[j];
  float best = 3.4e38f;
  int   bidx = 0;
  for (int k = 0; k < K; k += 2) {
    const float4* e0 = (const float4*)(cb + (k << 6));
    const float4* e1 = e0 + 16;
    float a0 = 0.f, a1 = 0.f, a2 = 0.f, a3 = 0.f;
    float b0 = 0.f, b1 = 0.f, b2 = 0.f, b3 = 0.f;
#pragma unroll
    for (int j = 0; j < 16; j += 4) {
      float4 tt;
      tt = e0[j + 0]; DOT4(a0, zr[j + 0], tt);
      tt = e1[j + 0]; DOT4(b0, zr[j + 0], tt);
      tt = e0[j + 1]; DOT4(a1, zr[j + 1], tt);
      tt = e1[j + 1]; DOT4(b1, zr[j + 1], tt);
      tt = e0[j + 2]; DOT4(a2, zr[j + 2], tt);
      tt = e1[j + 2]; DOT4(b2, zr[j + 2], tt);
      tt = e0[j + 3]; DOT4(a3, zr[j + 3], tt);
      tt = e1[j + 3]; DOT4(b3, zr[j + 3], tt);
    }
    float d0 = (a0 + a1) + (a2 + a3);
    float d1 = (b0 + b1) + (b2 + b3);
    float m0 = fmaf(-2.f, d0, norms[k]);
    float m1 = fmaf(-2.f, d1, norms[k + 1]);
    if (m0 < best) { best = m0; bidx = k; }
    if (m1 < best) { best = m1; bidx = k + 1; }
  }
  const float4* eb4 = (const float4*)(cb + ((size_t)bidx << 6));
  float4* o4 = (float4*)(zq + (size_t)row * D);
  float l0 = 0.f, l1 = 0.f, l2 = 0.f, l3 = 0.f;
#pragma unroll
  for (int j = 0; j < 16; j += 4) {
    float4 e;
    e = eb4[j + 0]; o4[j + 0] = e; SQD4(l0, zr[j + 0], e);
    e = eb4[j + 1]; o4[j + 1] = e; SQD4(l1, zr[j + 1], e);
    e = eb4[j + 2]; o4[j + 2] = e; SQD4(l2, zr[j + 2], e);
    e = eb4[j + 3]; o4[j + 3] = e; SQD4(l3, zr[j + 3], e);
  }
  float row_loss = (l0 + l1) + (l2 + l3);
  atomicAdd(&counts[bidx], 1u);
  __shared__ float redf[256];
  redf[tid] = row_loss;
  __syncthreads();
#pragma unroll
  for (int s = 128; s > 0; s >>= 1) {
    if (tid < s) redf[tid] += redf[tid + s];
    __syncthreads();
  }
  if (tid == 0) block_loss[blockIdx.x] = redf[0];
}

// ---------------- launch -------------
extern "C" void kernel_launch(void* const* d_in, const int* in_sizes, int n_in,
                              void* d_out, int out_size, void* d_ws, size_t ws_size,
                              hipStream_t stream) {
  const float* z  = (const float*)d_in[0];
  const float* cb = (const float*)d_in[1];
  float* out = (float*)d_out;

  unsigned int* counts     = (unsigned int*)d_ws;
  float*        block_loss = (float*)((char*)d_ws + 4096);

  hipMemsetAsync(d_ws, 0, 4096, stream);   // zero counts

  if (ws_size >= WS_MAIN_NEED) {
    vq_prep<<<dim3(4), dim3(256), 0, stream>>>(cb, (char*)d_ws);
    vq_mfma<<<dim3(NBLOCKS), dim3(256), 0, stream>>>(z, cb, (const char*)d_ws,
                                                     out, counts, block_loss);
    vq_finalize<<<dim3(1), dim3(1024), 0, stream>>>(counts, block_loss, out, NBLOCKS);
  } else {
    float* norms = (float*)((char*)d_ws + 12288);
    vq_norms_fb<<<dim3(4), dim3(256), 0, stream>>>(cb, norms);
    vq_main_fb<<<dim3(NROWS / 256), dim3(256), 0, stream>>>(z, cb, norms,
                                                            out, counts, block_loss);
    vq_finalize<<<dim3(1), dim3(1024), 0, stream>>>(counts, block_loss, out, 1024);
  }
}